// Round 7
// baseline (961.601 us; speedup 1.0000x reference)
//
#include <hip/hip_runtime.h>

#define NB  64
#define IC  2048
#define ID  16
#define DD  256
#define DDSQ 65536
#define PB  (DDSQ * NB)       // 4,194,304 floats = one full-batch matrix buffer
#define NSQ 11                // matrix squarings
#define NPI 7                 // finish matvecs: exponent 2^11 * 8 = 16384

// ---------------- stage 1: u[b,c,:] = x[b,c,:] @ W_c (32 batches/block) -----
template<int GBATCH>
__global__ __launch_bounds__(256, 2) void u_kernel(const float* __restrict__ caps,
                                                   const float* __restrict__ W,
                                                   float* __restrict__ U) {
    const int c  = blockIdx.x;
    const int b0 = blockIdx.y * GBATCH;
    const int t  = threadIdx.x;
    __shared__ float xsT[ID][GBATCH];
    if (t < GBATCH * 4) {
        const int b = t >> 2, q = (t & 3) * 4;
        const float4 x4 = *(const float4*)&caps[((size_t)(b0 + b) * IC + c) * ID + q];
        xsT[q + 0][b] = x4.x; xsT[q + 1][b] = x4.y;
        xsT[q + 2][b] = x4.z; xsT[q + 3][b] = x4.w;
    }
    float w[ID];
#pragma unroll
    for (int i = 0; i < ID; ++i) w[i] = W[((size_t)c * ID + i) * DD + t];
    __syncthreads();
    float acc[GBATCH] = {};
#pragma unroll 4
    for (int i = 0; i < ID; ++i) {
#pragma unroll
        for (int bq = 0; bq < GBATCH / 4; ++bq) {
            const float4 xv = *(const float4*)&xsT[i][4 * bq];
            acc[4 * bq + 0] = fmaf(xv.x, w[i], acc[4 * bq + 0]);
            acc[4 * bq + 1] = fmaf(xv.y, w[i], acc[4 * bq + 1]);
            acc[4 * bq + 2] = fmaf(xv.z, w[i], acc[4 * bq + 2]);
            acc[4 * bq + 3] = fmaf(xv.w, w[i], acc[4 * bq + 3]);
        }
    }
#pragma unroll
    for (int b = 0; b < GBATCH; ++b)
        U[((size_t)(b0 + b) * IC + c) * DD + t] = acc[b];
}

// ---- stage 2: partial C, 128x64 tile, 8x4 micro (32 scalar acc), K=1024 ----
// id: low6 = batch (same-XCD tiles per batch), tk = id>>6: tile = tk>>1, kch = tk&1
__global__ __launch_bounds__(256, 2)
void c_kernel(const float* __restrict__ U,
              float* __restrict__ P0, float* __restrict__ P1,
              float* __restrict__ Sc) {
    const int id   = blockIdx.x;
    const int bb   = id & 63;
    const int tk   = id >> 6;            // 0..15
    const int tile = tk >> 1, kch = tk & 1;
    const int tr = tile >> 2, tc = tile & 3;
    const int d0 = tr * 128, e0 = tc * 64;
    const int t  = threadIdx.x;
    const int td = t >> 4, te = t & 15;
    const int sr = t >> 5, sc4 = (t & 31) * 4;   // A staging map
    const int br = t >> 4, bc4 = (t & 15) * 4;   // B staging map
    __shared__ float Ad[32][128];
    __shared__ float Ae[32][64];
    __shared__ float red[256];
    float acc[8][4] = {};                // 32 floats, constant-indexed ONLY
    const float* Ub = U + (size_t)bb * IC * DD;
    const int k0 = kch * (IC / 2);
    for (int kb = k0; kb < k0 + IC / 2; kb += 32) {
        float4 ra[4], rb[2];
#pragma unroll
        for (int p = 0; p < 4; ++p)
            ra[p] = *(const float4*)&Ub[(size_t)(kb + p * 8 + sr) * DD + d0 + sc4];
#pragma unroll
        for (int p = 0; p < 2; ++p)
            rb[p] = *(const float4*)&Ub[(size_t)(kb + p * 16 + br) * DD + e0 + bc4];
        __syncthreads();
#pragma unroll
        for (int p = 0; p < 4; ++p) *(float4*)&Ad[p * 8 + sr][sc4] = ra[p];
#pragma unroll
        for (int p = 0; p < 2; ++p) *(float4*)&Ae[p * 16 + br][bc4] = rb[p];
        __syncthreads();
#pragma unroll 4
        for (int k = 0; k < 32; ++k) {
            const float4 aL = *(const float4*)&Ad[k][8 * td];
            const float4 aH = *(const float4*)&Ad[k][8 * td + 4];
            const float4 b4 = *(const float4*)&Ae[k][4 * te];
            const float av[8] = {aL.x, aL.y, aL.z, aL.w, aH.x, aH.y, aH.z, aH.w};
#pragma unroll
            for (int i = 0; i < 8; ++i) {
                acc[i][0] = fmaf(av[i], b4.x, acc[i][0]);
                acc[i][1] = fmaf(av[i], b4.y, acc[i][1]);
                acc[i][2] = fmaf(av[i], b4.z, acc[i][2]);
                acc[i][3] = fmaf(av[i], b4.w, acc[i][3]);
            }
        }
    }
    float* Pb = (kch ? P1 : P0) + (size_t)bb * DDSQ;
#pragma unroll
    for (int i = 0; i < 8; ++i)
        *(float4*)&Pb[(size_t)(d0 + 8 * td + i) * DD + e0 + 4 * te] =
            make_float4(acc[i][0], acc[i][1], acc[i][2], acc[i][3]);
    if ((tc >> 1) == tr) {               // diagonal-overlap tile: fused trace
        const int off = (tc & 1) * 64;   // local row == off + local col on diag
        float ts = 0.f;
#pragma unroll
        for (int i = 0; i < 8; ++i)
#pragma unroll
            for (int j = 0; j < 4; ++j)
                if (8 * td + i == off + 4 * te + j) ts += acc[i][j];
        red[t] = ts;
        __syncthreads();
        for (int s = 128; s > 0; s >>= 1) {
            if (t < s) red[t] += red[t + s];
            __syncthreads();
        }
        if (t == 0) atomicAdd(&Sc[bb], red[0]);
    }
}

// ---- E = (D/s)^2, 128x64 tile; ADD2 folds D = D0 + D1 on first squaring ----
template<bool ADD2>
__global__ __launch_bounds__(256, 2)
void sq_kernel(const float* __restrict__ D0, const float* __restrict__ D1,
               float* __restrict__ E,
               const float* __restrict__ s_in, float* __restrict__ s_out) {
    const int id   = blockIdx.x;          // 512 blocks
    const int bb   = id & 63;
    const int tile = id >> 6;             // 0..7
    const int tr = tile >> 2, tc = tile & 3;
    const int d0 = tr * 128, e0 = tc * 64;
    const int t  = threadIdx.x;
    const int td = t >> 4, te = t & 15;
    const int sr = t >> 5, sc4 = (t & 31) * 4;
    const int br = t >> 4, bc4 = (t & 15) * 4;
    __shared__ float Ad[32][128];
    __shared__ float Ae[32][64];
    __shared__ float red[256];
    float acc[8][4] = {};
    const size_t mb = (size_t)bb * DDSQ;
    const float s = s_in[bb];
    const float inv = 1.f / (s * s);
    for (int kb = 0; kb < DD; kb += 32) {
        float4 ra[4], rb[2];
#pragma unroll
        for (int p = 0; p < 4; ++p) {
            const size_t row = mb + (size_t)(kb + p * 8 + sr) * DD;
            ra[p] = *(const float4*)&D0[row + d0 + sc4];
            if (ADD2) {
                const float4 x = *(const float4*)&D1[row + d0 + sc4];
                ra[p].x += x.x; ra[p].y += x.y; ra[p].z += x.z; ra[p].w += x.w;
            }
        }
#pragma unroll
        for (int p = 0; p < 2; ++p) {
            const size_t row = mb + (size_t)(kb + p * 16 + br) * DD;
            rb[p] = *(const float4*)&D0[row + e0 + bc4];
            if (ADD2) {
                const float4 x = *(const float4*)&D1[row + e0 + bc4];
                rb[p].x += x.x; rb[p].y += x.y; rb[p].z += x.z; rb[p].w += x.w;
            }
        }
        __syncthreads();
#pragma unroll
        for (int p = 0; p < 4; ++p) *(float4*)&Ad[p * 8 + sr][sc4] = ra[p];
#pragma unroll
        for (int p = 0; p < 2; ++p) *(float4*)&Ae[p * 16 + br][bc4] = rb[p];
        __syncthreads();
#pragma unroll 4
        for (int k = 0; k < 32; ++k) {
            const float4 aL = *(const float4*)&Ad[k][8 * td];
            const float4 aH = *(const float4*)&Ad[k][8 * td + 4];
            const float4 b4 = *(const float4*)&Ae[k][4 * te];
            const float av[8] = {aL.x, aL.y, aL.z, aL.w, aH.x, aH.y, aH.z, aH.w};
#pragma unroll
            for (int i = 0; i < 8; ++i) {
                acc[i][0] = fmaf(av[i], b4.x, acc[i][0]);
                acc[i][1] = fmaf(av[i], b4.y, acc[i][1]);
                acc[i][2] = fmaf(av[i], b4.z, acc[i][2]);
                acc[i][3] = fmaf(av[i], b4.w, acc[i][3]);
            }
        }
    }
#pragma unroll
    for (int i = 0; i < 8; ++i)
#pragma unroll
        for (int j = 0; j < 4; ++j)
            acc[i][j] *= inv;
    float* Eb = E + mb;
#pragma unroll
    for (int i = 0; i < 8; ++i)
        *(float4*)&Eb[(size_t)(d0 + 8 * td + i) * DD + e0 + 4 * te] =
            make_float4(acc[i][0], acc[i][1], acc[i][2], acc[i][3]);
    if ((tc >> 1) == tr) {
        const int off = (tc & 1) * 64;
        float ts = 0.f;
#pragma unroll
        for (int i = 0; i < 8; ++i)
#pragma unroll
            for (int j = 0; j < 4; ++j)
                if (8 * td + i == off + 4 * te + j) ts += acc[i][j];
        red[t] = ts;
        __syncthreads();
        for (int s = 128; s > 0; s >>= 1) {
            if (t < s) red[t] += red[t + s];
            __syncthreads();
        }
        if (t == 0) atomicAdd(&s_out[bb], red[0]);
    }
}

// ------- finish: column start + NPI matvecs (no renorm; lambda1 ~ 1) --------
__global__ __launch_bounds__(256, 2) void finish_kernel(const float* __restrict__ Dm,
                                                        float* __restrict__ out) {
    const int b = blockIdx.x, t = threadIdx.x;
    const float* Db = Dm + (size_t)b * DDSQ;
    __shared__ float vs[DD];
    __shared__ float red[DD];
    __shared__ int   ridx[DD];
    red[t] = Db[(size_t)t * DD + t];
    ridx[t] = t;
    __syncthreads();
    for (int s = 128; s > 0; s >>= 1) {
        if (t < s && red[t + s] > red[t]) { red[t] = red[t + s]; ridx[t] = ridx[t + s]; }
        __syncthreads();
    }
    const int jmax0 = ridx[0];
    __syncthreads();
    float v = Db[(size_t)jmax0 * DD + t];   // symmetric: column == row
    for (int it = 0; it < NPI; ++it) {
        vs[t] = v;
        __syncthreads();
        float a = 0.f;
        const float* row = Db + (size_t)t * DD;
#pragma unroll 8
        for (int j = 0; j < DD; j += 4) {
            const float4 d4 = *(const float4*)&row[j];
            a = fmaf(d4.x, vs[j],     a);
            a = fmaf(d4.y, vs[j + 1], a);
            a = fmaf(d4.z, vs[j + 2], a);
            a = fmaf(d4.w, vs[j + 3], a);
        }
        __syncthreads();
        v = a;
    }
    vs[t] = v;
    red[t] = v * v;
    __syncthreads();
    for (int s = 128; s > 0; s >>= 1) {
        if (t < s) red[t] += red[t + s];
        __syncthreads();
    }
    const float nrm = sqrtf(red[0]);
    __syncthreads();
    red[t] = fabsf(v);
    ridx[t] = t;
    __syncthreads();
    for (int s = 128; s > 0; s >>= 1) {
        if (t < s && red[t + s] > red[t]) { red[t] = red[t + s]; ridx[t] = ridx[t + s]; }
        __syncthreads();
    }
    const float sgn = (vs[ridx[0]] < 0.f) ? -1.f : 1.f;
    out[(size_t)b * DD + t] = sgn * v / nrm;
}

extern "C" void kernel_launch(void* const* d_in, const int* in_sizes, int n_in,
                              void* d_out, int out_size, void* d_ws, size_t ws_size,
                              hipStream_t stream) {
    const float* caps = (const float*)d_in[0];   // (64, 2048, 16)
    const float* W    = (const float*)d_in[1];   // (2048, 16, 256)
    float* out = (float*)d_out;                  // (64, 256)
    float* ws  = (float*)d_ws;

    // layout: U = 8*PB @0 | A0 @8PB | A1 @9PB | Sc @10PB  (~168 MB, fit in R6)
    float* U  = ws;
    float* A0 = ws + (size_t)8 * PB;
    float* A1 = ws + (size_t)9 * PB;
    float* Sc = ws + (size_t)10 * PB;
    float* X  = ws;                  // sq ping-pong overlays dead U
    float* Y  = ws + PB;

    hipMemsetAsync(Sc, 0, 2048 * sizeof(float), stream);

    u_kernel<32><<<dim3(IC, 2), 256, 0, stream>>>(caps, W, U);
    c_kernel<<<1024, 256, 0, stream>>>(U, A0, A1, Sc);

    // first squaring folds A0+A1 -> X; then 10 plain squarings ping-pong X/Y
    sq_kernel<true><<<512, 256, 0, stream>>>(A0, A1, X, Sc, Sc + 64);
    float* ping = X;
    float* pong = Y;
    for (int it = 1; it < NSQ; ++it) {
        sq_kernel<false><<<512, 256, 0, stream>>>(ping, nullptr, pong,
                                                  Sc + it * 64, Sc + (it + 1) * 64);
        float* tmp = ping; ping = pong; pong = tmp;
    }

    finish_kernel<<<NB, 256, 0, stream>>>(ping, out);   // NSQ odd -> ping == X
}

// Round 8
// 774.661 us; speedup vs baseline: 1.2413x; 1.2413x over previous
//
#include <hip/hip_runtime.h>

#define NB  64
#define IC  2048
#define ID  16
#define DD  256
#define DDSQ 65536
#define PB  (DDSQ * NB)       // 4,194,304 floats = one full-batch matrix buffer
#define NSQ 11                // matrix squarings
#define NPI 7                 // finish matvecs: exponent 2^11 * 8 = 16384

// FMA into a NAMED float4 (SSA values only — no arrays, nothing to spill)
#define FMA4(c, s, v) { (c).x = fmaf((s), (v).x, (c).x); (c).y = fmaf((s), (v).y, (c).y); \
                        (c).z = fmaf((s), (v).z, (c).z); (c).w = fmaf((s), (v).w, (c).w); }
#define F4Z make_float4(0.f, 0.f, 0.f, 0.f)
#define SCL4(c, s) { (c).x *= (s); (c).y *= (s); (c).z *= (s); (c).w *= (s); }
#define ADDF4(a, b) { (a).x += (b).x; (a).y += (b).y; (a).z += (b).z; (a).w += (b).w; }
// diagonal-trace contribution of micro-row i held in named float4 ci
#define TRC(ci, i) { if (8*td+(i) == off+4*te+0) ts += (ci).x; \
                     if (8*td+(i) == off+4*te+1) ts += (ci).y; \
                     if (8*td+(i) == off+4*te+2) ts += (ci).z; \
                     if (8*td+(i) == off+4*te+3) ts += (ci).w; }
#define STROW(dst, ci, i) *(float4*)&(dst)[(size_t)(d0 + 8*td + (i)) * DD + e0 + 4*te] = (ci);

// ---------------- stage 1: u[b,c,:] = x[b,c,:] @ W_c (16 batches/block) -----
__global__ __launch_bounds__(256, 4) void u_kernel(const float* __restrict__ caps,
                                                   const float* __restrict__ W,
                                                   float* __restrict__ U) {
    const int c  = blockIdx.x;
    const int b0 = blockIdx.y * 16;
    const int t  = threadIdx.x;
    __shared__ float xsT[ID][16];        // [dim][batch]
    if (t < 64) {
        const int b = t >> 2, q = (t & 3) * 4;
        const float4 x4 = *(const float4*)&caps[((size_t)(b0 + b) * IC + c) * ID + q];
        xsT[q + 0][b] = x4.x; xsT[q + 1][b] = x4.y;
        xsT[q + 2][b] = x4.z; xsT[q + 3][b] = x4.w;
    }
    __syncthreads();
    float a0 = 0.f, a1 = 0.f, a2 = 0.f, a3 = 0.f, a4 = 0.f, a5 = 0.f, a6 = 0.f, a7 = 0.f;
    float a8 = 0.f, a9 = 0.f, a10 = 0.f, a11 = 0.f, a12 = 0.f, a13 = 0.f, a14 = 0.f, a15 = 0.f;
#pragma unroll
    for (int i = 0; i < ID; ++i) {
        const float wi = W[((size_t)c * ID + i) * DD + t];    // coalesced over t
        const float4 x0 = *(const float4*)&xsT[i][0];
        const float4 x1 = *(const float4*)&xsT[i][4];
        const float4 x2 = *(const float4*)&xsT[i][8];
        const float4 x3 = *(const float4*)&xsT[i][12];
        a0  = fmaf(x0.x, wi, a0 );  a1  = fmaf(x0.y, wi, a1 );
        a2  = fmaf(x0.z, wi, a2 );  a3  = fmaf(x0.w, wi, a3 );
        a4  = fmaf(x1.x, wi, a4 );  a5  = fmaf(x1.y, wi, a5 );
        a6  = fmaf(x1.z, wi, a6 );  a7  = fmaf(x1.w, wi, a7 );
        a8  = fmaf(x2.x, wi, a8 );  a9  = fmaf(x2.y, wi, a9 );
        a10 = fmaf(x2.z, wi, a10);  a11 = fmaf(x2.w, wi, a11);
        a12 = fmaf(x3.x, wi, a12);  a13 = fmaf(x3.y, wi, a13);
        a14 = fmaf(x3.z, wi, a14);  a15 = fmaf(x3.w, wi, a15);
    }
    U[((size_t)(b0 +  0) * IC + c) * DD + t] = a0;
    U[((size_t)(b0 +  1) * IC + c) * DD + t] = a1;
    U[((size_t)(b0 +  2) * IC + c) * DD + t] = a2;
    U[((size_t)(b0 +  3) * IC + c) * DD + t] = a3;
    U[((size_t)(b0 +  4) * IC + c) * DD + t] = a4;
    U[((size_t)(b0 +  5) * IC + c) * DD + t] = a5;
    U[((size_t)(b0 +  6) * IC + c) * DD + t] = a6;
    U[((size_t)(b0 +  7) * IC + c) * DD + t] = a7;
    U[((size_t)(b0 +  8) * IC + c) * DD + t] = a8;
    U[((size_t)(b0 +  9) * IC + c) * DD + t] = a9;
    U[((size_t)(b0 + 10) * IC + c) * DD + t] = a10;
    U[((size_t)(b0 + 11) * IC + c) * DD + t] = a11;
    U[((size_t)(b0 + 12) * IC + c) * DD + t] = a12;
    U[((size_t)(b0 + 13) * IC + c) * DD + t] = a13;
    U[((size_t)(b0 + 14) * IC + c) * DD + t] = a14;
    U[((size_t)(b0 + 15) * IC + c) * DD + t] = a15;
}

// ---- stage 2: partial C, 128x64 tile, 8x4 micro (named float4 acc) ---------
// id: low6 = batch (same-XCD tiles per batch); tk = id>>6: tile = tk>>1, kch = tk&1
__global__ __launch_bounds__(256, 4)
void c_kernel(const float* __restrict__ U,
              float* __restrict__ P0, float* __restrict__ P1,
              float* __restrict__ Sc) {
    const int id   = blockIdx.x;
    const int bb   = id & 63;
    const int tk   = id >> 6;            // 0..15
    const int tile = tk >> 1, kch = tk & 1;
    const int tr = tile >> 2, tc = tile & 3;
    const int d0 = tr * 128, e0 = tc * 64;
    const int t  = threadIdx.x;
    const int td = t >> 4, te = t & 15;
    const int sr = t >> 5, sc4 = (t & 31) * 4;   // A staging map
    const int br = t >> 4, bc4 = (t & 15) * 4;   // B staging map
    __shared__ float Ad[32][128];
    __shared__ float Ae[32][64];
    __shared__ float red[256];
    float4 c0 = F4Z, c1 = F4Z, c2 = F4Z, c3 = F4Z;
    float4 c4 = F4Z, c5 = F4Z, c6 = F4Z, c7 = F4Z;
    const float* Ub = U + (size_t)bb * IC * DD;
    const int k0 = kch * (IC / 2);
    for (int kb = k0; kb < k0 + IC / 2; kb += 32) {
        const float4 ra0 = *(const float4*)&Ub[(size_t)(kb +  0 + sr) * DD + d0 + sc4];
        const float4 ra1 = *(const float4*)&Ub[(size_t)(kb +  8 + sr) * DD + d0 + sc4];
        const float4 ra2 = *(const float4*)&Ub[(size_t)(kb + 16 + sr) * DD + d0 + sc4];
        const float4 ra3 = *(const float4*)&Ub[(size_t)(kb + 24 + sr) * DD + d0 + sc4];
        const float4 rb0 = *(const float4*)&Ub[(size_t)(kb +  0 + br) * DD + e0 + bc4];
        const float4 rb1 = *(const float4*)&Ub[(size_t)(kb + 16 + br) * DD + e0 + bc4];
        __syncthreads();
        *(float4*)&Ad[ 0 + sr][sc4] = ra0;
        *(float4*)&Ad[ 8 + sr][sc4] = ra1;
        *(float4*)&Ad[16 + sr][sc4] = ra2;
        *(float4*)&Ad[24 + sr][sc4] = ra3;
        *(float4*)&Ae[ 0 + br][bc4] = rb0;
        *(float4*)&Ae[16 + br][bc4] = rb1;
        __syncthreads();
#pragma unroll 4
        for (int k = 0; k < 32; ++k) {
            const float4 aL = *(const float4*)&Ad[k][8 * td];
            const float4 aH = *(const float4*)&Ad[k][8 * td + 4];
            const float4 b4 = *(const float4*)&Ae[k][4 * te];
            FMA4(c0, aL.x, b4); FMA4(c1, aL.y, b4); FMA4(c2, aL.z, b4); FMA4(c3, aL.w, b4);
            FMA4(c4, aH.x, b4); FMA4(c5, aH.y, b4); FMA4(c6, aH.z, b4); FMA4(c7, aH.w, b4);
        }
    }
    float* Pb = (kch ? P1 : P0) + (size_t)bb * DDSQ;
    STROW(Pb, c0, 0); STROW(Pb, c1, 1); STROW(Pb, c2, 2); STROW(Pb, c3, 3);
    STROW(Pb, c4, 4); STROW(Pb, c5, 5); STROW(Pb, c6, 6); STROW(Pb, c7, 7);
    if ((tc >> 1) == tr) {               // diagonal-overlap tile: fused trace
        const int off = (tc & 1) * 64;
        float ts = 0.f;
        TRC(c0, 0); TRC(c1, 1); TRC(c2, 2); TRC(c3, 3);
        TRC(c4, 4); TRC(c5, 5); TRC(c6, 6); TRC(c7, 7);
        red[t] = ts;
        __syncthreads();
        for (int s = 128; s > 0; s >>= 1) {
            if (t < s) red[t] += red[t + s];
            __syncthreads();
        }
        if (t == 0) atomicAdd(&Sc[bb], red[0]);
    }
}

// ---- E = (D/s)^2, 128x64 tile; ADD2 folds D = D0 + D1 on first squaring ----
template<bool ADD2>
__global__ __launch_bounds__(256, 4)
void sq_kernel(const float* __restrict__ D0, const float* __restrict__ D1,
               float* __restrict__ E,
               const float* __restrict__ s_in, float* __restrict__ s_out) {
    const int id   = blockIdx.x;          // 512 blocks
    const int bb   = id & 63;
    const int tile = id >> 6;             // 0..7
    const int tr = tile >> 2, tc = tile & 3;
    const int d0 = tr * 128, e0 = tc * 64;
    const int t  = threadIdx.x;
    const int td = t >> 4, te = t & 15;
    const int sr = t >> 5, sc4 = (t & 31) * 4;
    const int br = t >> 4, bc4 = (t & 15) * 4;
    __shared__ float Ad[32][128];
    __shared__ float Ae[32][64];
    __shared__ float red[256];
    float4 c0 = F4Z, c1 = F4Z, c2 = F4Z, c3 = F4Z;
    float4 c4 = F4Z, c5 = F4Z, c6 = F4Z, c7 = F4Z;
    const size_t mb = (size_t)bb * DDSQ;
    const float s = s_in[bb];
    const float inv = 1.f / (s * s);
    for (int kb = 0; kb < DD; kb += 32) {
        const size_t r0 = mb + (size_t)(kb +  0 + sr) * DD + d0 + sc4;
        const size_t r1 = mb + (size_t)(kb +  8 + sr) * DD + d0 + sc4;
        const size_t r2 = mb + (size_t)(kb + 16 + sr) * DD + d0 + sc4;
        const size_t r3 = mb + (size_t)(kb + 24 + sr) * DD + d0 + sc4;
        const size_t q0 = mb + (size_t)(kb +  0 + br) * DD + e0 + bc4;
        const size_t q1 = mb + (size_t)(kb + 16 + br) * DD + e0 + bc4;
        float4 ra0 = *(const float4*)&D0[r0];
        float4 ra1 = *(const float4*)&D0[r1];
        float4 ra2 = *(const float4*)&D0[r2];
        float4 ra3 = *(const float4*)&D0[r3];
        float4 rb0 = *(const float4*)&D0[q0];
        float4 rb1 = *(const float4*)&D0[q1];
        if (ADD2) {
            const float4 xa0 = *(const float4*)&D1[r0]; ADDF4(ra0, xa0);
            const float4 xa1 = *(const float4*)&D1[r1]; ADDF4(ra1, xa1);
            const float4 xa2 = *(const float4*)&D1[r2]; ADDF4(ra2, xa2);
            const float4 xa3 = *(const float4*)&D1[r3]; ADDF4(ra3, xa3);
            const float4 xb0 = *(const float4*)&D1[q0]; ADDF4(rb0, xb0);
            const float4 xb1 = *(const float4*)&D1[q1]; ADDF4(rb1, xb1);
        }
        __syncthreads();
        *(float4*)&Ad[ 0 + sr][sc4] = ra0;
        *(float4*)&Ad[ 8 + sr][sc4] = ra1;
        *(float4*)&Ad[16 + sr][sc4] = ra2;
        *(float4*)&Ad[24 + sr][sc4] = ra3;
        *(float4*)&Ae[ 0 + br][bc4] = rb0;
        *(float4*)&Ae[16 + br][bc4] = rb1;
        __syncthreads();
#pragma unroll 4
        for (int k = 0; k < 32; ++k) {
            const float4 aL = *(const float4*)&Ad[k][8 * td];
            const float4 aH = *(const float4*)&Ad[k][8 * td + 4];
            const float4 b4 = *(const float4*)&Ae[k][4 * te];
            FMA4(c0, aL.x, b4); FMA4(c1, aL.y, b4); FMA4(c2, aL.z, b4); FMA4(c3, aL.w, b4);
            FMA4(c4, aH.x, b4); FMA4(c5, aH.y, b4); FMA4(c6, aH.z, b4); FMA4(c7, aH.w, b4);
        }
    }
    SCL4(c0, inv); SCL4(c1, inv); SCL4(c2, inv); SCL4(c3, inv);
    SCL4(c4, inv); SCL4(c5, inv); SCL4(c6, inv); SCL4(c7, inv);
    float* Eb = E + mb;
    STROW(Eb, c0, 0); STROW(Eb, c1, 1); STROW(Eb, c2, 2); STROW(Eb, c3, 3);
    STROW(Eb, c4, 4); STROW(Eb, c5, 5); STROW(Eb, c6, 6); STROW(Eb, c7, 7);
    if ((tc >> 1) == tr) {
        const int off = (tc & 1) * 64;
        float ts = 0.f;
        TRC(c0, 0); TRC(c1, 1); TRC(c2, 2); TRC(c3, 3);
        TRC(c4, 4); TRC(c5, 5); TRC(c6, 6); TRC(c7, 7);
        red[t] = ts;
        __syncthreads();
        for (int s2 = 128; s2 > 0; s2 >>= 1) {
            if (t < s2) red[t] += red[t + s2];
            __syncthreads();
        }
        if (t == 0) atomicAdd(&s_out[bb], red[0]);
    }
}

// ------- finish: column start + NPI matvecs (no renorm; lambda1 ~ 1) --------
__global__ __launch_bounds__(256, 2) void finish_kernel(const float* __restrict__ Dm,
                                                        float* __restrict__ out) {
    const int b = blockIdx.x, t = threadIdx.x;
    const float* Db = Dm + (size_t)b * DDSQ;
    __shared__ float vs[DD];
    __shared__ float red[DD];
    __shared__ int   ridx[DD];
    red[t] = Db[(size_t)t * DD + t];
    ridx[t] = t;
    __syncthreads();
    for (int s = 128; s > 0; s >>= 1) {
        if (t < s && red[t + s] > red[t]) { red[t] = red[t + s]; ridx[t] = ridx[t + s]; }
        __syncthreads();
    }
    const int jmax0 = ridx[0];
    __syncthreads();
    float v = Db[(size_t)jmax0 * DD + t];   // symmetric: column == row
    for (int it = 0; it < NPI; ++it) {
        vs[t] = v;
        __syncthreads();
        float a = 0.f;
        const float* row = Db + (size_t)t * DD;
#pragma unroll 8
        for (int j = 0; j < DD; j += 4) {
            const float4 d4 = *(const float4*)&row[j];
            a = fmaf(d4.x, vs[j],     a);
            a = fmaf(d4.y, vs[j + 1], a);
            a = fmaf(d4.z, vs[j + 2], a);
            a = fmaf(d4.w, vs[j + 3], a);
        }
        __syncthreads();
        v = a;
    }
    vs[t] = v;
    red[t] = v * v;
    __syncthreads();
    for (int s = 128; s > 0; s >>= 1) {
        if (t < s) red[t] += red[t + s];
        __syncthreads();
    }
    const float nrm = sqrtf(red[0]);
    __syncthreads();
    red[t] = fabsf(v);
    ridx[t] = t;
    __syncthreads();
    for (int s = 128; s > 0; s >>= 1) {
        if (t < s && red[t + s] > red[t]) { red[t] = red[t + s]; ridx[t] = ridx[t + s]; }
        __syncthreads();
    }
    const float sgn = (vs[ridx[0]] < 0.f) ? -1.f : 1.f;
    out[(size_t)b * DD + t] = sgn * v / nrm;
}

extern "C" void kernel_launch(void* const* d_in, const int* in_sizes, int n_in,
                              void* d_out, int out_size, void* d_ws, size_t ws_size,
                              hipStream_t stream) {
    const float* caps = (const float*)d_in[0];   // (64, 2048, 16)
    const float* W    = (const float*)d_in[1];   // (2048, 16, 256)
    float* out = (float*)d_out;                  // (64, 256)
    float* ws  = (float*)d_ws;

    // layout: U = 8*PB @0 | A0 @8PB | A1 @9PB | Sc @10PB  (~168 MB, fit in R7)
    float* U  = ws;
    float* A0 = ws + (size_t)8 * PB;
    float* A1 = ws + (size_t)9 * PB;
    float* Sc = ws + (size_t)10 * PB;
    float* X  = ws;                  // sq ping-pong overlays dead U
    float* Y  = ws + PB;

    hipMemsetAsync(Sc, 0, 2048 * sizeof(float), stream);

    u_kernel<<<dim3(IC, 4), 256, 0, stream>>>(caps, W, U);
    c_kernel<<<1024, 256, 0, stream>>>(U, A0, A1, Sc);

    // first squaring folds A0+A1 -> X; then 10 plain squarings ping-pong X/Y
    sq_kernel<true><<<512, 256, 0, stream>>>(A0, A1, X, Sc, Sc + 64);
    float* ping = X;
    float* pong = Y;
    for (int it = 1; it < NSQ; ++it) {
        sq_kernel<false><<<512, 256, 0, stream>>>(ping, nullptr, pong,
                                                  Sc + it * 64, Sc + (it + 1) * 64);
        float* tmp = ping; ping = pong; pong = tmp;
    }

    finish_kernel<<<NB, 256, 0, stream>>>(ping, out);   // NSQ odd -> ping == X
}